// Round 7
// baseline (461.545 us; speedup 1.0000x reference)
//
#include <hip/hip_runtime.h>
#include <hip/hip_bf16.h>
#include <math.h>

// B=8, P=2048, Q=1024, H=1024
// R7: flash-style fusion. Pipeline:
//   1. convert k,q,Wk,Wq fp32->fp16 (one launch)
//   2. proj_q GEMM: qkey16 = relu(q16 @ Wq16^T)  (R5-verified 128x128 kernel)
//   3. qT16 = transpose(q) fp16
//   4. fused_attn (one launch, 256 blocks = 8 batches x 32 p-blocks):
//      per block (batch b, rows p0..p0+63):
//      ph0: pk = relu(k16[rows] @ Wk16^T) SWAPPED (C^T frags -> contiguous-h
//           ds_write_b64) -> pk_lds [64p][1024h] (XOR-swizzled 16B slots)
//      phA: S^T[q,p] = qkey @ pk^T; qkey A-frags DIRECT from L2 (2MB/batch,
//           32x reuse; staging would be overhead); pk B-frags from LDS
//      softmax over q (= rows of S^T): in-lane 32 + shfl_xor(16,32) + 8-wave
//           LDS reduce; alphas fp32 written directly (required output);
//           P f16 overwrites pk_lds (dead after phA)
//      phB: ctx[p,d] = P @ qT^T; P A-frags from LDS, qT B-frags direct L2;
//           free-running (no barriers)
//   Eliminates: scores GEMM + softmax kernel + proj_k launch + pkey16 and
//   alphas round-trips (~290 MB HBM) + 2 launches.
// blockIdx&7 = batch -> each XCD's 32 CUs share one batch's qkey/qT in L2.
// LDS: pk/P 128KB + stage dbuf 16KB + red 4KB = 148KB -> 1 block/CU.

typedef _Float16 v8h __attribute__((ext_vector_type(8)));
typedef _Float16 v4h __attribute__((ext_vector_type(4)));
typedef float v4f __attribute__((ext_vector_type(4)));

#define AS1C(p) ((const __attribute__((address_space(1))) void*)(p))
#define AS3(p)  ((__attribute__((address_space(3))) void*)(p))
#define MFMA16 __builtin_amdgcn_mfma_f32_16x16x32_f16

// ---------------------------------------------------------------------------
// Fused attention: one block = one batch x 64 p-rows. 512 thr = 8 waves.
__global__ __launch_bounds__(512) void fused_attn(
    const _Float16* __restrict__ k16,      // [B*2048, 1024]
    const _Float16* __restrict__ Wk16,     // [1024, 1024]
    const _Float16* __restrict__ qkey16,   // [B*1024, 1024]
    const _Float16* __restrict__ qT16,     // [B][1024 d][1024 q]
    const unsigned char* __restrict__ qmask, // [B, 1024]
    float* __restrict__ ctx,               // [B*2048, 1024]
    float* __restrict__ alphas)            // [B*2048, 1024]
{
  extern __shared__ _Float16 lds[];
  _Float16* Pk   = lds;                    // [64][1024] f16 = 128KB: pk, then P
  _Float16* Sbuf = lds + 65536;            // stage dbuf 2 x 4096 f16 (16KB)
  float*    red1 = (float*)(lds + 73728);  // 512 f32 (2KB)
  float*    red2 = (float*)(lds + 74752);  // 512 f32 (2KB)

  const int bz   = blockIdx.x & 7;         // batch == XCD (round-robin)
  const int pblk = blockIdx.x >> 3;        // 0..31
  const int p0   = pblk * 64;

  const int t  = threadIdx.x;
  const int l  = t & 63;
  const int w  = t >> 6;                   // 0..7
  const int fr = l & 15;
  const int fq = l >> 4;
  const int w128 = w * 128;
  // swizzled 16B-slot offsets (f16 elems) for kh=0/1 fragment reads of a
  // 64-row (row&7-XOR) or 1024-col (same formula, low-3-bit XOR) tile.
  const int sa0 = (fq ^ (fr & 7)) * 8;
  const int sa1 = ((4 + fq) ^ (fr & 7)) * 8;

  // staging thread map: row = t>>3 (0..63), phys slot = t&7,
  // pre-swizzled global col = ((t&7) ^ (row&7)) * 8
  const int trow = t >> 3;
  const int tswz = ((t & 7) ^ (trow & 7)) * 8;

  const _Float16* Kst = k16 + ((long long)(bz * 2048 + p0 + trow)) * 1024 + tswz;
  const _Float16* qkb = qkey16 + (long long)bz * 1048576;
  const _Float16* qTb = qT16   + (long long)bz * 1048576;
  float* ctxb = ctx    + (long long)(bz * 2048 + p0) * 1024;
  float* alpb = alphas + (long long)(bz * 2048 + p0) * 1024;
  const unsigned char* mskb = qmask + bz * 1024;

  // ======================= phase 0: pk = relu(k @ Wk^T), swapped =========
  // C0^T[m=h][n=p] = sum_d Wk16[h,d] * k16[p,d];  pkey[p][h] = C0^T[h][p].
  {
    v4f acc0[8][4];
#pragma unroll
    for (int i = 0; i < 8; ++i)
#pragma unroll
      for (int j = 0; j < 4; ++j)
        acc0[i][j] = (v4f){0.f, 0.f, 0.f, 0.f};

#define STAGE0(kt) __builtin_amdgcn_global_load_lds( \
      AS1C(Kst + ((long long)(kt) << 6)), AS3(Sbuf + (((kt) & 1) << 12) + t * 8), 16, 0, 0)

    STAGE0(0);
    for (int kt = 0; kt < 16; ++kt) {
      if (kt < 15) {
        STAGE0(kt + 1);
        asm volatile("s_waitcnt vmcnt(1)" ::: "memory");
      } else {
        asm volatile("s_waitcnt vmcnt(0)" ::: "memory");
      }
      __builtin_amdgcn_sched_barrier(0);
      __builtin_amdgcn_s_barrier();
      asm volatile("" ::: "memory");

      const _Float16* Bs = Sbuf + ((kt & 1) << 12);
      v8h b0[4], b1[4];
#pragma unroll
      for (int j = 0; j < 4; ++j) {
        b0[j] = *(const v8h*)&Bs[(j * 16 + fr) * 64 + sa0];
        b1[j] = *(const v8h*)&Bs[(j * 16 + fr) * 64 + sa1];
      }
#pragma unroll
      for (int i = 0; i < 8; ++i) {
        const v8h a0 = *(const v8h*)&Wk16[(long long)(w128 + i * 16 + fr) * 1024 + kt * 64 + fq * 8];
        const v8h a1 = *(const v8h*)&Wk16[(long long)(w128 + i * 16 + fr) * 1024 + kt * 64 + 32 + fq * 8];
#pragma unroll
        for (int j = 0; j < 4; ++j) {
          acc0[i][j] = MFMA16(a0, b0[j], acc0[i][j], 0, 0, 0);
          acc0[i][j] = MFMA16(a1, b1[j], acc0[i][j], 0, 0, 0);
        }
      }
      asm volatile("s_waitcnt lgkmcnt(0)" ::: "memory");
      __builtin_amdgcn_sched_barrier(0);
      __builtin_amdgcn_s_barrier();
    }
#undef STAGE0

    // epilogue: relu -> f16 -> Pk[p][h], swizzled. Per (i,j): 4 consecutive h
    // (rows of C0^T) at fixed p -> one ds_write_b64.
#pragma unroll
    for (int i = 0; i < 8; ++i) {
#pragma unroll
      for (int j = 0; j < 4; ++j) {
        v4f v = acc0[i][j];
        v4h h4 = {(_Float16)fmaxf(v[0], 0.f), (_Float16)fmaxf(v[1], 0.f),
                  (_Float16)fmaxf(v[2], 0.f), (_Float16)fmaxf(v[3], 0.f)};
        const int p   = j * 16 + fr;
        const int s16 = w * 16 + i * 2 + (fq >> 1);
        const int phys = (s16 & ~7) | ((s16 & 7) ^ (p & 7));
        *(v4h*)&Pk[p * 1024 + phys * 8 + (fq & 1) * 4] = h4;
      }
    }
    __syncthreads();   // pk ready for all waves
  }

  // ======================= phase A: S^T = qkey @ pk^T ====================
  // C[m=q][n=p] = sum_h qkey[q,h] * pk[p,h]. No barriers in loop.
  float M4[4], IV[4];
  {
    v4f acc[8][4];
#pragma unroll
    for (int i = 0; i < 8; ++i)
#pragma unroll
      for (int j = 0; j < 4; ++j)
        acc[i][j] = (v4f){0.f, 0.f, 0.f, 0.f};

    for (int kt = 0; kt < 16; ++kt) {
      v8h pb0[4], pb1[4];
#pragma unroll
      for (int j = 0; j < 4; ++j) {
        pb0[j] = *(const v8h*)&Pk[(j * 16 + fr) * 1024 + kt * 64 + sa0];
        pb1[j] = *(const v8h*)&Pk[(j * 16 + fr) * 1024 + kt * 64 + sa1];
      }
#pragma unroll
      for (int i = 0; i < 8; ++i) {
        const v8h a0 = *(const v8h*)&qkb[(long long)(w128 + i * 16 + fr) * 1024 + kt * 64 + fq * 8];
        const v8h a1 = *(const v8h*)&qkb[(long long)(w128 + i * 16 + fr) * 1024 + kt * 64 + 32 + fq * 8];
#pragma unroll
        for (int j = 0; j < 4; ++j) {
          acc[i][j] = MFMA16(a0, pb0[j], acc[i][j], 0, 0, 0);
          acc[i][j] = MFMA16(a1, pb1[j], acc[i][j], 0, 0, 0);
        }
      }
    }

    // ---- mask (q axis = rows of S^T; lane's q = w128 + i*16 + fq*4 + r) ----
#pragma unroll
    for (int i = 0; i < 8; ++i) {
      const unsigned m4 = *(const unsigned*)&mskb[w128 + i * 16 + fq * 4];
      if (m4) {
#pragma unroll
        for (int r = 0; r < 4; ++r)
          if ((m4 >> (8 * r)) & 0xFF) {
#pragma unroll
            for (int j = 0; j < 4; ++j) acc[i][j][r] = -INFINITY;
          }
      }
    }

    // ---- row max over q: in-lane (i,r) + xor fq(16,32) + cross-wave LDS ----
#pragma unroll
    for (int j = 0; j < 4; ++j) {
      float pm = -INFINITY;
#pragma unroll
      for (int i = 0; i < 8; ++i) {
        pm = fmaxf(pm, fmaxf(fmaxf(acc[i][j][0], acc[i][j][1]),
                             fmaxf(acc[i][j][2], acc[i][j][3])));
      }
      pm = fmaxf(pm, __shfl_xor(pm, 16, 64));
      pm = fmaxf(pm, __shfl_xor(pm, 32, 64));
      if (fq == 0) red1[(j * 16 + fr) * 8 + w] = pm;
    }
    __syncthreads();
#pragma unroll
    for (int j = 0; j < 4; ++j) {
      const float* r = &red1[(j * 16 + fr) * 8];
      M4[j] = fmaxf(fmaxf(fmaxf(r[0], r[1]), fmaxf(r[2], r[3])),
                    fmaxf(fmaxf(r[4], r[5]), fmaxf(r[6], r[7])));
    }

    // ---- exp + row sum ----
#pragma unroll
    for (int j = 0; j < 4; ++j) {
      float ps = 0.f;
#pragma unroll
      for (int i = 0; i < 8; ++i) {
#pragma unroll
        for (int r = 0; r < 4; ++r) {
          const float e = __expf(acc[i][j][r] - M4[j]);
          acc[i][j][r] = e;
          ps += e;
        }
      }
      ps += __shfl_xor(ps, 16, 64);
      ps += __shfl_xor(ps, 32, 64);
      if (fq == 0) red2[(j * 16 + fr) * 8 + w] = ps;
    }
    __syncthreads();
#pragma unroll
    for (int j = 0; j < 4; ++j) {
      const float* r = &red2[(j * 16 + fr) * 8];
      IV[j] = 1.f / (r[0] + r[1] + r[2] + r[3] + r[4] + r[5] + r[6] + r[7]);
    }

    // ---- write alphas fp32 (output) + P f16 into Pk (pk dead) ----
#pragma unroll
    for (int i = 0; i < 8; ++i) {
#pragma unroll
      for (int j = 0; j < 4; ++j) {
        float4 o;
        o.x = acc[i][j][0] * IV[j];
        o.y = acc[i][j][1] * IV[j];
        o.z = acc[i][j][2] * IV[j];
        o.w = acc[i][j][3] * IV[j];
        const int p = j * 16 + fr;
        *(float4*)&alpb[(long long)p * 1024 + w128 + i * 16 + fq * 4] = o;
        v4h h4 = {(_Float16)o.x, (_Float16)o.y, (_Float16)o.z, (_Float16)o.w};
        const int s16  = w * 16 + i * 2 + (fq >> 1);
        const int phys = (s16 & ~7) | ((s16 & 7) ^ (p & 7));
        *(v4h*)&Pk[p * 1024 + phys * 8 + (fq & 1) * 4] = h4;
      }
    }
    __syncthreads();   // P ready; all pk reads long done
  }

  // ======================= phase B: ctx = P @ qT^T =======================
  // C[m=p][n=d] = sum_q P[p,q] * qT[d,q]. Free-running.
  {
    v4f acc2[4][8];
#pragma unroll
    for (int i = 0; i < 4; ++i)
#pragma unroll
      for (int j = 0; j < 8; ++j)
        acc2[i][j] = (v4f){0.f, 0.f, 0.f, 0.f};

    for (int kt = 0; kt < 16; ++kt) {
      v8h pa0[4], pa1[4];
#pragma unroll
      for (int i = 0; i < 4; ++i) {
        pa0[i] = *(const v8h*)&Pk[(i * 16 + fr) * 1024 + kt * 64 + sa0];
        pa1[i] = *(const v8h*)&Pk[(i * 16 + fr) * 1024 + kt * 64 + sa1];
      }
#pragma unroll
      for (int j = 0; j < 8; ++j) {
        const v8h b0 = *(const v8h*)&qTb[(long long)(w128 + j * 16 + fr) * 1024 + kt * 64 + fq * 8];
        const v8h b1 = *(const v8h*)&qTb[(long long)(w128 + j * 16 + fr) * 1024 + kt * 64 + 32 + fq * 8];
#pragma unroll
        for (int i = 0; i < 4; ++i) {
          acc2[i][j] = MFMA16(pa0[i], b0, acc2[i][j], 0, 0, 0);
          acc2[i][j] = MFMA16(pa1[i], b1, acc2[i][j], 0, 0, 0);
        }
      }
    }

#pragma unroll
    for (int i = 0; i < 4; ++i) {
#pragma unroll
      for (int j = 0; j < 8; ++j) {
#pragma unroll
        for (int r = 0; r < 4; ++r) {
          ctxb[(long long)(i * 16 + fq * 4 + r) * 1024 + w128 + j * 16 + fr] = acc2[i][j][r];
        }
      }
    }
  }
}

// ---------------------------------------------------------------------------
// NT MFMA GEMM (R5-verified): C[m,n] = sum_k A[m,k]*B[n,k]. 128x128, BK=64,
// 256 thr, 2 blk/CU, NT-fastest decode + XCD chunking, both-sides swizzle.
__global__ __launch_bounds__(256) void gemm_nt_f16_128(
    const _Float16* __restrict__ A, const _Float16* __restrict__ B,
    float* __restrict__ Cf, _Float16* __restrict__ Ch,
    int N, int K, int Mtiles, int Ntiles,
    long long sA, long long sB, long long sC, int relu)
{
  extern __shared__ _Float16 lds[];

  const int nwg = gridDim.x;
  const int cpx = nwg >> 3;
  const int bid = (blockIdx.x & 7) * cpx + (blockIdx.x >> 3);
  const int nt  = bid % Ntiles;
  const int mt  = (bid / Ntiles) % Mtiles;
  const int bz  = bid / (Mtiles * Ntiles);

  A += (long long)bz * sA;
  const _Float16* Bp = B + (long long)bz * sB;

  const int m0 = mt * 128;
  const int n0 = nt * 128;
  const int t  = threadIdx.x;
  const int l  = t & 63;
  const int w  = t >> 6;
  const int wm = (w >> 1) * 64;
  const int wn = (w & 1) * 64;
  const int fr = l & 15;
  const int fq = l >> 4;
  const int r3 = fr & 7;
  const int sa0 = (fq ^ r3) * 8;
  const int sa1 = ((4 + fq) ^ r3) * 8;

  const int trow = t >> 3;
  const int tswz = ((t & 7) ^ (trow & 7)) * 8;

  const _Float16* Ast = A  + (long long)(m0 + trow) * K + tswz;
  const _Float16* Bst = Bp + (long long)(n0 + trow) * K + tswz;

  v4f acc[4][4];
#pragma unroll
  for (int i = 0; i < 4; ++i)
#pragma unroll
    for (int j = 0; j < 4; ++j)
      acc[i][j] = (v4f){0.f, 0.f, 0.f, 0.f};

  const int NT = K >> 6;

#define STAGE(kt) do {                                                                   \
    _Float16* s_ = lds + (((kt) & 1) << 14);                                             \
    const long long ko_ = (long long)((kt) << 6);                                        \
    __builtin_amdgcn_global_load_lds(AS1C(Ast + ko_),            AS3(s_ +         t * 8), 16, 0, 0); \
    __builtin_amdgcn_global_load_lds(AS1C(Ast + 32LL * K + ko_), AS3(s_ +  2048 + t * 8), 16, 0, 0); \
    __builtin_amdgcn_global_load_lds(AS1C(Ast + 64LL * K + ko_), AS3(s_ +  4096 + t * 8), 16, 0, 0); \
    __builtin_amdgcn_global_load_lds(AS1C(Ast + 96LL * K + ko_), AS3(s_ +  6144 + t * 8), 16, 0, 0); \
    __builtin_amdgcn_global_load_lds(AS1C(Bst + ko_),            AS3(s_ +  8192 + t * 8), 16, 0, 0); \
    __builtin_amdgcn_global_load_lds(AS1C(Bst + 32LL * K + ko_), AS3(s_ + 10240 + t * 8), 16, 0, 0); \
    __builtin_amdgcn_global_load_lds(AS1C(Bst + 64LL * K + ko_), AS3(s_ + 12288 + t * 8), 16, 0, 0); \
    __builtin_amdgcn_global_load_lds(AS1C(Bst + 96LL * K + ko_), AS3(s_ + 14336 + t * 8), 16, 0, 0); \
  } while (0)

  STAGE(0);

  for (int kt = 0; kt < NT; ++kt) {
    if (kt + 1 < NT) {
      STAGE(kt + 1);
      asm volatile("s_waitcnt vmcnt(8)" ::: "memory");
    } else {
      asm volatile("s_waitcnt vmcnt(0)" ::: "memory");
    }
    __builtin_amdgcn_sched_barrier(0);
    __builtin_amdgcn_s_barrier();
    asm volatile("" ::: "memory");

    const _Float16* Ab = lds + ((kt & 1) << 14);
    const _Float16* Bb = Ab + 8192;

    v8h a0[4], a1[4], b0[4], b1[4];
#pragma unroll
    for (int i = 0; i < 4; ++i) {
      a0[i] = *(const v8h*)&Ab[(wm + i * 16 + fr) * 64 + sa0];
      a1[i] = *(const v8h*)&Ab[(wm + i * 16 + fr) * 64 + sa1];
    }
#pragma unroll
    for (int j = 0; j < 2; ++j) {
      b0[j] = *(const v8h*)&Bb[(wn + j * 16 + fr) * 64 + sa0];
      b1[j] = *(const v8h*)&Bb[(wn + j * 16 + fr) * 64 + sa1];
    }
    __builtin_amdgcn_s_setprio(1);
#pragma unroll
    for (int i = 0; i < 4; ++i)
#pragma unroll
      for (int j = 0; j < 2; ++j) {
        acc[i][j] = MFMA16(a0[i], b0[j], acc[i][j], 0, 0, 0);
        acc[i][j] = MFMA16(a1[i], b1[j], acc[i][j], 0, 0, 0);
      }
    __builtin_amdgcn_s_setprio(0);

#pragma unroll
    for (int j = 2; j < 4; ++j) {
      b0[j] = *(const v8h*)&Bb[(wn + j * 16 + fr) * 64 + sa0];
      b1[j] = *(const v8h*)&Bb[(wn + j * 16 + fr) * 64 + sa1];
    }
    __builtin_amdgcn_s_setprio(1);
#pragma unroll
    for (int i = 0; i < 4; ++i)
#pragma unroll
      for (int j = 2; j < 4; ++j) {
        acc[i][j] = MFMA16(a0[i], b0[j], acc[i][j], 0, 0, 0);
        acc[i][j] = MFMA16(a1[i], b1[j], acc[i][j], 0, 0, 0);
      }
    __builtin_amdgcn_s_setprio(0);

    asm volatile("s_waitcnt lgkmcnt(0)" ::: "memory");
    __builtin_amdgcn_sched_barrier(0);
    __builtin_amdgcn_s_barrier();
  }
#undef STAGE

  float* Cfb = Cf ? Cf + (long long)bz * sC : nullptr;
  _Float16* Chb = Ch ? Ch + (long long)bz * sC : nullptr;
#pragma unroll
  for (int i = 0; i < 4; ++i) {
#pragma unroll
    for (int j = 0; j < 4; ++j) {
#pragma unroll
      for (int r = 0; r < 4; ++r) {
        const int row = m0 + wm + i * 16 + fq * 4 + r;
        const int col = n0 + wn + j * 16 + fr;
        float v = acc[i][j][r];
        if (relu) v = fmaxf(v, 0.f);
        if (Cfb) Cfb[(long long)row * N + col] = v;
        if (Chb) Chb[(long long)row * N + col] = (_Float16)v;
      }
    }
  }
}

// ---------------------------------------------------------------------------
__global__ __launch_bounds__(256) void convert_all_kernel(
    const float* __restrict__ s0, _Float16* __restrict__ d0, int b0,  // k
    const float* __restrict__ s1, _Float16* __restrict__ d1, int b1,  // q
    const float* __restrict__ s2, _Float16* __restrict__ d2, int b2,  // Wk
    const float* __restrict__ s3, _Float16* __restrict__ d3)          // Wq
{
  int blk = blockIdx.x;
  const float* src;
  _Float16* dst;
  if (blk < b0)           { src = s0; dst = d0; }
  else if (blk < b0 + b1) { src = s1; dst = d1; blk -= b0; }
  else if (blk < b0 + b1 + b2) { src = s2; dst = d2; blk -= b0 + b1; }
  else                    { src = s3; dst = d3; blk -= b0 + b1 + b2; }
  const long long i = ((long long)blk * 256 + threadIdx.x) * 4;
  const float4 v = *(const float4*)(src + i);
  v4h o = {(_Float16)v.x, (_Float16)v.y, (_Float16)v.z, (_Float16)v.w};
  *(v4h*)(dst + i) = o;
}

// q [B,Q,H] fp32 -> qT [B,H,Q] fp16, 64x64 tiles
__global__ __launch_bounds__(256) void transpose_f16_kernel(
    const float* __restrict__ q, _Float16* __restrict__ qT, int Q, int H)
{
  __shared__ float tile[64][65];
  const float* qb = q + (long long)blockIdx.z * Q * H;
  _Float16* qTb = qT + (long long)blockIdx.z * H * Q;
  const int q0 = blockIdx.x * 64, h0 = blockIdx.y * 64;
  const int t = threadIdx.x;
  const int tr = t >> 4, tc = (t & 15) << 2;
#pragma unroll
  for (int i = 0; i < 4; ++i) {
    const float4 v = *(const float4*)(qb + (long long)(q0 + tr + i * 16) * H + h0 + tc);
    tile[tr + i * 16][tc + 0] = v.x;
    tile[tr + i * 16][tc + 1] = v.y;
    tile[tr + i * 16][tc + 2] = v.z;
    tile[tr + i * 16][tc + 3] = v.w;
  }
  __syncthreads();
#pragma unroll
  for (int i = 0; i < 4; ++i) {
    const int hl = tr + i * 16;
    const int ql = tc;
    v4h o = {(_Float16)tile[ql + 0][hl], (_Float16)tile[ql + 1][hl],
             (_Float16)tile[ql + 2][hl], (_Float16)tile[ql + 3][hl]};
    *(v4h*)(qTb + (long long)(h0 + hl) * Q + q0 + ql) = o;
  }
}

// ---------------------------------------------------------------------------
extern "C" void kernel_launch(void* const* d_in, const int* in_sizes, int n_in,
                              void* d_out, int out_size, void* d_ws, size_t ws_size,
                              hipStream_t stream)
{
  const int B = 8, P = 2048, Q = 1024, H = 1024;
  const float* k  = (const float*)d_in[0];
  const float* q  = (const float*)d_in[1];
  const unsigned char* qmask = (const unsigned char*)d_in[2];
  const float* Wk = (const float*)d_in[3];
  const float* Wq = (const float*)d_in[4];

  float* ctx    = (float*)d_out;                  // [B,P,H] fp32
  float* alphas = ctx + (size_t)B * P * H;        // [B,P,Q] fp32

  char* wsb = (char*)d_ws;
  _Float16* qkey16 = (_Float16*)(wsb);                        // 16.78 MB
  _Float16* k16    = (_Float16*)(wsb + 16777216);             // 33.55 MB
  _Float16* q16    = (_Float16*)(wsb + 16777216 + 33554432);  // 16.78 MB
  _Float16* qT16   = q16;                                     // q16 dead after proj_q
  _Float16* Wk16   = (_Float16*)(wsb + 67108864);
  _Float16* Wq16   = (_Float16*)(wsb + 69206016);

  const long long nK = (long long)B * P * H;   // 16.78M
  const long long nQ = (long long)B * Q * H;   // 8.39M
  const long long nW = (long long)H * H;       // 1.05M

  // 1. fused converts
  const int bK = (int)(nK / 1024), bQ = (int)(nQ / 1024), bW = (int)(nW / 1024);
  convert_all_kernel<<<bK + bQ + 2 * bW, 256, 0, stream>>>(
      k, k16, bK, q, q16, bQ, Wk, Wk16, bW, Wq, Wq16);

  // 2. proj_q: qkey16 = relu(q16 @ Wq16^T)  [8192 x 1024]
  gemm_nt_f16_128<<<64 * 8, 256, 65536, stream>>>(
      q16, Wq16, nullptr, qkey16, H, H, 64, 8, 0LL, 0LL, 0LL, 1);

  // 3. qT16 = q^T fp16 (overwrites q16)
  transpose_f16_kernel<<<dim3(Q / 64, H / 64, B), 256, 0, stream>>>(q, qT16, Q, H);

  // 4. fused: proj_k rows + scores + softmax + alphas write + ctx
  fused_attn<<<256, 512, 151552, stream>>>(
      k16, Wk16, qkey16, qT16, qmask, ctx, alphas);
}